// Round 10
// baseline (1413.982 us; speedup 1.0000x reference)
//
#include <hip/hip_runtime.h>
#include <stdint.h>

// LSTM (B=128, T=512, I=64, H=512) persistent kernel, round 10:
//  - protocol = round-4/9 EXACTLY (proven): 32 groups x 8 blocks, tag-embedded
//    u64 granules {u32 tag, 2xbf16} at MALL, relaxed agent atomics, single
//    dwordx4 sc1 poll (flag IS data), one barrier/step.
//  - NEW 1: x prefetched ONE STEP AHEAD (issued post-barrier, lands during
//    h-MFMA+gates) -> poll's vmcnt(0) no longer eats x L2-miss latency
//    (r9 analysis: x is ~all of FETCH_SIZE, 8x redundant, L2-thrashing).
//  - NEW 2: gate redistribution via 4 shuffles: lane (lk,lrow) computes the
//    single (batch=lk, col=lrow) gate -> exp 16->4/thread, gate VALU ~1/4,
//    cst 8->2 regs, zero redundant lanes.
//  - Keeps: DPP-paired dword LDS scatter (0 conflicts), masked b128 reads,
//    4 independent MFMA chains, bf16-x prep kernel (ws-gated), LDS classifier.

#define T_STEPS 512
#define HID 512
#define IND 64
#define NGROUPS 32
#define BPG 8           // blocks per group
#define BATCH_PG 4      // batches per group
#define UPB 64          // hidden units per block
#define NTHREADS 512    // 8 waves
#define NBLK (NGROUPS * BPG)
#define XBF_OFF (512 * 1024)
#define XBF_ELEMS (128 * T_STEPS * IND)

typedef float f32x4 __attribute__((ext_vector_type(4)));
typedef short s16x8 __attribute__((ext_vector_type(8)));
typedef unsigned u32x4 __attribute__((ext_vector_type(4)));
typedef unsigned long long u64_t;

#define ALOADU(p)    __hip_atomic_load((p), __ATOMIC_RELAXED, __HIP_MEMORY_SCOPE_AGENT)
#define ASTOREU(p,v) __hip_atomic_store((p), (v), __ATOMIC_RELAXED, __HIP_MEMORY_SCOPE_AGENT)

__device__ inline unsigned short f2bf(float f) {
  uint32_t u = __builtin_bit_cast(uint32_t, f);
  u += 0x7fffu + ((u >> 16) & 1u);   // RNE (finite inputs)
  return (unsigned short)(u >> 16);
}

__device__ inline s16x8 pack8(f32x4 a, f32x4 b) {
  s16x8 r;
  r[0] = (short)f2bf(a[0]); r[1] = (short)f2bf(a[1]);
  r[2] = (short)f2bf(a[2]); r[3] = (short)f2bf(a[3]);
  r[4] = (short)f2bf(b[0]); r[5] = (short)f2bf(b[1]);
  r[6] = (short)f2bf(b[2]); r[7] = (short)f2bf(b[3]);
  return r;
}

template <int CTRL>
__device__ inline float qbc(float v) {   // quad_perm broadcast via DPP (VALU)
  int i = __builtin_bit_cast(int, v);
  return __builtin_bit_cast(float,
      __builtin_amdgcn_update_dpp(i, i, CTRL, 0xF, 0xF, false));
}

__device__ inline unsigned qswap(unsigned v) {  // quad_perm [1,0,3,2]
  int i = __builtin_bit_cast(int, v);
  return (unsigned)__builtin_amdgcn_update_dpp(i, i, 0xB1, 0xF, 0xF, false);
}

// one 16B sc1 (device-coherent, MALL) load of a granule pair. EARLY-CLOBBER.
__device__ inline void ld4_sc1(const u64_t* p, u64_t& a, u64_t& b) {
  u32x4 r;
  asm volatile("global_load_dwordx4 %0, %1, off sc1\n\ts_waitcnt vmcnt(0)"
               : "=&v"(r) : "v"(p) : "memory");
  a = ((u64_t)r[1] << 32) | r[0];
  b = ((u64_t)r[3] << 32) | r[2];
}

// prep: x f32 -> bf16 (same [b][t][i] layout)
__global__ void __launch_bounds__(256) xconv(const float* __restrict__ x,
                                             unsigned short* __restrict__ xb) {
  const int stride = gridDim.x * blockDim.x;
  for (int i = blockIdx.x * blockDim.x + threadIdx.x; i < XBF_ELEMS / 4; i += stride) {
    const f32x4 v = ((const f32x4*)x)[i];
    u64_t o = (u64_t)f2bf(v[0]) | ((u64_t)f2bf(v[1]) << 16) |
              ((u64_t)f2bf(v[2]) << 32) | ((u64_t)f2bf(v[3]) << 48);
    ((u64_t*)xb)[i] = o;
  }
}

template <bool XBF>
__global__ void __launch_bounds__(NTHREADS, 2)
lstm_persist(const float* __restrict__ x,   const float* __restrict__ Wih,
             const float* __restrict__ Whh, const float* __restrict__ bih,
             const float* __restrict__ bhh, const float* __restrict__ Wcls,
             const float* __restrict__ bcls, float* __restrict__ out,
             u64_t* __restrict__ hx,                 // [2][NGROUPS][1024], memset 0
             const unsigned short* __restrict__ xbf) // bf16 x or null
{
  __shared__ unsigned short hsm[2][4 * HID];      // 2 x 4KB A-tile (rows 0..3)
  __shared__ float clsh[BATCH_PG][UPB];           // final-h for classifier

  const int g    = blockIdx.x >> 3;
  const int blk  = blockIdx.x & 7;
  const int tid  = threadIdx.x;
  const int w    = tid >> 6;
  const int lane = tid & 63;
  const int lrow = lane & 15;   // A row / D col
  const int lk   = lane >> 4;   // K subgroup / (post-shuffle) batch index

  // ---- persistent weight fragments: 2 col-tiles x 18 K-chunks ----
  s16x8 wf[2][18];
  float bias[2];
#pragma unroll
  for (int n = 0; n < 2; ++n) {
    const int c    = w * 32 + n * 16 + lrow;       // local gate-col 0..255
    const int grow = (c & 3) * HID + blk * UPB + (c >> 2);
#pragma unroll
    for (int kk = 0; kk < 16; ++kk) {
      const float* p = Whh + (size_t)grow * HID + kk * 32 + lk * 8;
      wf[n][kk] = pack8(*(const f32x4*)p, *(const f32x4*)(p + 4));
    }
#pragma unroll
    for (int kk = 0; kk < 2; ++kk) {
      const float* p = Wih + (size_t)grow * IND + kk * 32 + lk * 8;
      wf[n][16 + kk] = pack8(*(const f32x4*)p, *(const f32x4*)(p + 4));
    }
    bias[n] = bih[grow] + bhh[grow];
  }

  const bool is_gg = ((lrow & 3) == 2);           // tanh gate column
  const bool arow  = (lrow < BATCH_PG);           // lanes holding real A rows
  float cst[2] = {0.f, 0.f};                       // c-state: (batch lk, unit lrow>>2)
  float hn2[2];

  // persistent A fragments: inactive lanes stay zero forever (masked loads)
  s16x8 ah[4] = {};
  s16x8 ax0 = {}, ax1 = {};

  const int xb = g * BATCH_PG + (lrow & 3);
  const float* xrow = x + (size_t)xb * (T_STEPS * IND) + lk * 8;
  const unsigned short* xbrow = XBF ? (xbf + (size_t)xb * (T_STEPS * IND) + lk * 8)
                                    : (const unsigned short*)nullptr;

  // prologue: x for t=0
  if (arow) {
    if (XBF) {
      ax0 = *(const s16x8*)(xbrow);
      ax1 = *(const s16x8*)(xbrow + 32);
    } else {
      ax0 = pack8(*(const f32x4*)xrow,        *(const f32x4*)(xrow + 4));
      ax1 = pack8(*(const f32x4*)(xrow + 32), *(const f32x4*)(xrow + 36));
    }
  }

  // precomputed scatter constants (DPP-paired dword writes)
  const bool evn = (tid & 1) == 0;
  const int  ue  = tid & ~1;
  const int  sc_base = ((ue >> 3) << 4) + (ue & 7) * 2;   // slot*16 + byte
  const int  addr01 = (evn ? 0 : 1024) + (sc_base ^ (evn ? 0 : (4 << 4)));
  const int  addr23 = (evn ? 2048 : 3072) + (sc_base ^ (evn ? (8 << 4) : (12 << 4)));

  for (int t = 0; t < T_STEPS; ++t) {
    const int rb = t & 1;
    const unsigned tg = (unsigned)t;

    // poll own granule pair until tag == t (flag IS data); 1 transaction/iter
    const u64_t* gp = hx + ((size_t)(rb * NGROUPS + g) << 10) + 2 * tid;
    u64_t v0, v1;
    ld4_sc1(gp, v0, v1);
    while ((unsigned)v0 != tg || (unsigned)v1 != tg) ld4_sc1(gp, v0, v1);
    const unsigned hp0 = (unsigned)(v0 >> 32), hp1 = (unsigned)(v1 >> 32);

    // scatter: pair halves with quad neighbor -> 2 full-dword LDS writes
    {
      char* hb = (char*)hsm[rb];
      const unsigned q0 = qswap(hp0), q1 = qswap(hp1);
      const unsigned v01 = evn ? ((hp0 & 0xffffu) | (q0 << 16))
                               : ((q0 >> 16) | (hp0 & 0xffff0000u));
      const unsigned v23 = evn ? ((hp1 & 0xffffu) | (q1 << 16))
                               : ((q1 >> 16) | (hp1 & 0xffff0000u));
      *(unsigned*)(hb + addr01) = v01;
      *(unsigned*)(hb + addr23) = v23;
    }

    // x MFMAs seed 4 independent chains while the tile settles
    f32x4 acc00 = {0.f, 0.f, 0.f, 0.f}, acc01 = {0.f, 0.f, 0.f, 0.f};
    f32x4 acc10 = {0.f, 0.f, 0.f, 0.f}, acc11 = {0.f, 0.f, 0.f, 0.f};
    acc00 = __builtin_amdgcn_mfma_f32_16x16x32_bf16(ax0, wf[0][16], acc00, 0, 0, 0);
    acc01 = __builtin_amdgcn_mfma_f32_16x16x32_bf16(ax1, wf[0][17], acc01, 0, 0, 0);
    acc10 = __builtin_amdgcn_mfma_f32_16x16x32_bf16(ax0, wf[1][16], acc10, 0, 0, 0);
    acc11 = __builtin_amdgcn_mfma_f32_16x16x32_bf16(ax1, wf[1][17], acc11, 0, 0, 0);

    __syncthreads();

    // PREFETCH next step's x NOW: lands during h-MFMA+gates, so the next
    // poll's vmcnt(0) never waits on an x L2 miss (serial-chain removal)
    s16x8 axn0 = {}, axn1 = {};
    {
      const int tn = (t + 1 < T_STEPS) ? t + 1 : t;
      if (arow) {
        if (XBF) {
          axn0 = *(const s16x8*)(xbrow + (size_t)tn * IND);
          axn1 = *(const s16x8*)(xbrow + (size_t)tn * IND + 32);
        } else {
          const float* p = xrow + (size_t)tn * IND;
          axn0 = pack8(*(const f32x4*)p,        *(const f32x4*)(p + 4));
          axn1 = pack8(*(const f32x4*)(p + 32), *(const f32x4*)(p + 36));
        }
      }
    }

    // h MFMAs: masked reads (16 active lanes); two chains per col-tile
    const char* rowp = (const char*)hsm[rb] + lrow * 1024;
    const int rxor = lrow << 2;   // slot ^= (row*4); slot granule = 16B
#pragma unroll
    for (int kk4 = 0; kk4 < 4; ++kk4) {
      if (arow) {
#pragma unroll
        for (int j = 0; j < 4; ++j)
          ah[j] = *(const s16x8*)(rowp + (((16 * kk4 + 4 * j + lk) ^ rxor) << 4));
      }
#pragma unroll
      for (int j = 0; j < 4; ++j) {
        const int kk = kk4 * 4 + j;
        if (kk4 < 2) {
          acc00 = __builtin_amdgcn_mfma_f32_16x16x32_bf16(ah[j], wf[0][kk], acc00, 0, 0, 0);
          acc10 = __builtin_amdgcn_mfma_f32_16x16x32_bf16(ah[j], wf[1][kk], acc10, 0, 0, 0);
        } else {
          acc01 = __builtin_amdgcn_mfma_f32_16x16x32_bf16(ah[j], wf[0][kk], acc01, 0, 0, 0);
          acc11 = __builtin_amdgcn_mfma_f32_16x16x32_bf16(ah[j], wf[1][kk], acc11, 0, 0, 0);
        }
      }
    }

    // redistribute: lane (lk,lrow) <- D[batch lk][col lrow] per tile
    float myv[2];
#pragma unroll
    for (int n = 0; n < 2; ++n) {
      const f32x4 aA = n ? acc10 : acc00;
      const f32x4 aB = n ? acc11 : acc01;
      const float s0 = aA[0] + aB[0], s1 = aA[1] + aB[1];
      const float s2 = aA[2] + aB[2], s3 = aA[3] + aB[3];
      const float b0 = __shfl(s0, lrow), b1 = __shfl(s1, lrow);
      const float b2 = __shfl(s2, lrow), b3 = __shfl(s3, lrow);
      myv[n] = (lk == 0) ? b0 : (lk == 1) ? b1 : (lk == 2) ? b2 : b3;
    }

    // gates: ONE (batch,col) per lane (exp 16->4/thread vs pre-r10)
#pragma unroll
    for (int n = 0; n < 2; ++n) {
      const float v  = myv[n] + bias[n];
      const float a  = is_gg ? (2.f * v) : (-v);
      const float e  = __expf(a);
      const float r1 = __builtin_amdgcn_rcpf(1.f + e);
      const float sg = is_gg ? (1.f - 2.f * r1) : r1;   // tanh or sigmoid
      const float vi = qbc<0x00>(sg);
      const float vf = qbc<0x55>(sg);
      const float vg = qbc<0xAA>(sg);
      const float vo = qbc<0xFF>(sg);
      const float c  = fmaf(vf, cst[n], vi * vg);
      cst[n] = c;
      const float th = 1.f - 2.f * __builtin_amdgcn_rcpf(1.f + __expf(2.f * c));
      hn2[n] = vo * th;
    }

    // producers: pack {batch lk, lk+1} via shfl_down(16); lanes lk in {0,2},
    // lrow%4==0 store one granule each (layout identical to pre-r10)
    u64_t* op = hx + ((size_t)((rb ^ 1) * NGROUPS + g) << 10);
    const u64_t ntg = (u64_t)(unsigned)(t + 1);
#pragma unroll
    for (int n = 0; n < 2; ++n) {
      const unsigned hb16 = (unsigned)f2bf(hn2[n]);
      const unsigned pk   = hb16 | (__shfl_down(hb16, 16) << 16);
      if ((lrow & 3) == 0) {
        const int ul = w * 8 + n * 4 + (lrow >> 2);     // local unit 0..63
        if ((lk & 1) == 0) {
          const int gu = blk * UPB + ul;                // global unit 0..511
          ASTOREU(op + 2 * gu + (lk >> 1), ntg | ((u64_t)pk << 32));
        }
        if (t == T_STEPS - 1) clsh[lk][ul] = hn2[n];
      }
    }

    ax0 = axn0; ax1 = axn1;
  }

  // ---- classifier: per-block partials over its 64 units ----
  __syncthreads();
  if (w == 0) {
#pragma unroll
    for (int b = 0; b < BATCH_PG; ++b) {
      const float hv = clsh[b][lane];
      for (int cls = 0; cls < 10; ++cls) {
        float v = hv * Wcls[(size_t)cls * HID + blk * UPB + lane];
#pragma unroll
        for (int m = 32; m >= 1; m >>= 1) v += __shfl_xor(v, m);
        if (lane == 0) {
          if (blk == 0) v += bcls[cls];
          atomicAdd(&out[(g * BATCH_PG + b) * 10 + cls], v);
        }
      }
    }
  }
}

extern "C" void kernel_launch(void* const* d_in, const int* in_sizes, int n_in,
                              void* d_out, int out_size, void* d_ws, size_t ws_size,
                              hipStream_t stream) {
  const float* x    = (const float*)d_in[0];
  const float* Wih  = (const float*)d_in[1];
  const float* Whh  = (const float*)d_in[2];
  const float* bih  = (const float*)d_in[3];
  const float* bhh  = (const float*)d_in[4];
  const float* Wcls = (const float*)d_in[5];
  const float* bcls = (const float*)d_in[6];
  float* out = (float*)d_out;

  u64_t* hx = (u64_t*)d_ws;   // [2][32][1024] u64 = 512 KiB
  const bool use_xbf = ws_size >= (size_t)XBF_OFF + (size_t)XBF_ELEMS * 2;
  unsigned short* xbf = use_xbf ? (unsigned short*)((uint8_t*)d_ws + XBF_OFF) : nullptr;

  // replay-safe re-init: zero tags (tag0 == step-0 data h=0) and output accum
  hipMemsetAsync(hx, 0, 2 * NGROUPS * 1024 * sizeof(u64_t), stream);
  hipMemsetAsync(out, 0, (size_t)out_size * sizeof(float), stream);
  if (use_xbf) xconv<<<dim3(2048), dim3(256), 0, stream>>>(x, xbf);

  const unsigned short* xbfc = xbf;
  void* args[] = {&x, &Wih, &Whh, &bih, &bhh, &Wcls, &bcls, &out, &hx, &xbfc};
  if (use_xbf) {
    hipError_t e = hipLaunchCooperativeKernel(
        reinterpret_cast<const void*>(&lstm_persist<true>), dim3(NBLK),
        dim3(NTHREADS), args, 0, stream);
    if (e != hipSuccess)
      lstm_persist<true><<<dim3(NBLK), dim3(NTHREADS), 0, stream>>>(
          x, Wih, Whh, bih, bhh, Wcls, bcls, out, hx, xbfc);
  } else {
    hipError_t e = hipLaunchCooperativeKernel(
        reinterpret_cast<const void*>(&lstm_persist<false>), dim3(NBLK),
        dim3(NTHREADS), args, 0, stream);
    if (e != hipSuccess)
      lstm_persist<false><<<dim3(NBLK), dim3(NTHREADS), 0, stream>>>(
          x, Wih, Whh, bih, bhh, Wcls, bcls, out, hx, xbfc);
  }
}

// Round 11
// 1154.384 us; speedup vs baseline: 1.2249x; 1.2249x over previous
//
#include <hip/hip_runtime.h>
#include <stdint.h>

// LSTM (B=128, T=512, I=64, H=512) persistent kernel, round 11:
//  - protocol = round-4/9/10 EXACTLY (proven): 32 groups x 8 blocks, tag-embedded
//    u64 granules {u32 tag, 2xbf16} at MALL, relaxed agent atomics, one
//    barrier/step, poll IS the data load.
//  - NEW 1: 2-deep PING-PONG poll in a single asm block (pinned v[112:119]):
//    two dwordx4 sc1 loads in flight, wait vmcnt(1), check oldest, reissue on
//    stale -> sample spacing RT/2 instead of RT (kills detect quantization,
//    the only non-HW term left in the measured ~2.3us comm wait).
//    Safe vs r6's hang class: whole loop is one asm block; leftover in-flight
//    load is always the wave's OLDEST vmem op -> compiler waitcnts stay valid.
//  - NEW 2: x-MFMAs hoisted BEFORE the poll (depend only on prefetched ax).
//  - NEW 3: producer stores interleaved per col-tile with gate math (earlier
//    visibility head start on half the granules).
//  - Keeps: DPP-paired dword LDS scatter (0 conflicts), masked b128 reads,
//    gate redistribution (1 gate/lane), x one-step prefetch, bf16-x prep
//    kernel (ws-gated), LDS classifier.

#define T_STEPS 512
#define HID 512
#define IND 64
#define NGROUPS 32
#define BPG 8           // blocks per group
#define BATCH_PG 4      // batches per group
#define UPB 64          // hidden units per block
#define NTHREADS 512    // 8 waves
#define NBLK (NGROUPS * BPG)
#define XBF_OFF (512 * 1024)
#define XBF_ELEMS (128 * T_STEPS * IND)

typedef float f32x4 __attribute__((ext_vector_type(4)));
typedef short s16x8 __attribute__((ext_vector_type(8)));
typedef unsigned long long u64_t;

#define ASTOREU(p,v) __hip_atomic_store((p), (v), __ATOMIC_RELAXED, __HIP_MEMORY_SCOPE_AGENT)

__device__ inline unsigned short f2bf(float f) {
  uint32_t u = __builtin_bit_cast(uint32_t, f);
  u += 0x7fffu + ((u >> 16) & 1u);   // RNE (finite inputs)
  return (unsigned short)(u >> 16);
}

__device__ inline s16x8 pack8(f32x4 a, f32x4 b) {
  s16x8 r;
  r[0] = (short)f2bf(a[0]); r[1] = (short)f2bf(a[1]);
  r[2] = (short)f2bf(a[2]); r[3] = (short)f2bf(a[3]);
  r[4] = (short)f2bf(b[0]); r[5] = (short)f2bf(b[1]);
  r[6] = (short)f2bf(b[2]); r[7] = (short)f2bf(b[3]);
  return r;
}

template <int CTRL>
__device__ inline float qbc(float v) {   // quad_perm broadcast via DPP (VALU)
  int i = __builtin_bit_cast(int, v);
  return __builtin_bit_cast(float,
      __builtin_amdgcn_update_dpp(i, i, CTRL, 0xF, 0xF, false));
}

__device__ inline unsigned qswap(unsigned v) {  // quad_perm [1,0,3,2]
  int i = __builtin_bit_cast(int, v);
  return (unsigned)__builtin_amdgcn_update_dpp(i, i, 0xB1, 0xF, 0xF, false);
}

// 2-deep ping-pong poll of one 16B granule pair until both embedded tags == tg.
// Returns the two data dwords. Pinned buffers v[112:115] / v[116:119]; sample
// spacing ~RT/2. Leftover in-flight load (clobbered regs) is drained by the
// next call's entry vmcnt(0); intermediate compiler waits remain correct since
// our load is always the oldest outstanding vmem op (in-order completion).
__device__ inline void poll2(const u64_t* p, unsigned tg, unsigned& d0, unsigned& d1) {
  asm volatile(
    "s_waitcnt vmcnt(0)\n\t"                        // exact vmcnt bookkeeping
    "global_load_dwordx4 v[112:115], %2, off sc1\n\t"
    "global_load_dwordx4 v[116:119], %2, off sc1\n\t"
    "1:\n\t"
    "s_waitcnt vmcnt(1)\n\t"                        // oldest -> v[112:115]
    "v_cmp_eq_u32 vcc, %3, v112\n\t"
    "v_cmp_eq_u32 s[48:49], %3, v114\n\t"
    "s_and_b64 s[48:49], s[48:49], vcc\n\t"
    "s_xor_b64 s[50:51], s[48:49], exec\n\t"        // SCC=1 iff some lane stale
    "s_cbranch_scc0 2f\n\t"
    "global_load_dwordx4 v[112:115], %2, off sc1\n\t"
    "s_waitcnt vmcnt(1)\n\t"                        // oldest -> v[116:119]
    "v_cmp_eq_u32 vcc, %3, v116\n\t"
    "v_cmp_eq_u32 s[48:49], %3, v118\n\t"
    "s_and_b64 s[48:49], s[48:49], vcc\n\t"
    "s_xor_b64 s[50:51], s[48:49], exec\n\t"
    "s_cbranch_scc0 3f\n\t"
    "global_load_dwordx4 v[116:119], %2, off sc1\n\t"
    "s_branch 1b\n\t"
    "2:\n\t"
    "v_mov_b32 %0, v113\n\t"
    "v_mov_b32 %1, v115\n\t"
    "s_branch 4f\n\t"
    "3:\n\t"
    "v_mov_b32 %0, v117\n\t"
    "v_mov_b32 %1, v119\n\t"
    "4:\n\t"
    : "=&v"(d0), "=&v"(d1)
    : "v"(p), "s"(tg)
    : "v112","v113","v114","v115","v116","v117","v118","v119",
      "s48","s49","s50","s51","vcc","scc","memory");
}

// prep: x f32 -> bf16 (same [b][t][i] layout)
__global__ void __launch_bounds__(256) xconv(const float* __restrict__ x,
                                             unsigned short* __restrict__ xb) {
  const int stride = gridDim.x * blockDim.x;
  for (int i = blockIdx.x * blockDim.x + threadIdx.x; i < XBF_ELEMS / 4; i += stride) {
    const f32x4 v = ((const f32x4*)x)[i];
    u64_t o = (u64_t)f2bf(v[0]) | ((u64_t)f2bf(v[1]) << 16) |
              ((u64_t)f2bf(v[2]) << 32) | ((u64_t)f2bf(v[3]) << 48);
    ((u64_t*)xb)[i] = o;
  }
}

template <bool XBF>
__global__ void __launch_bounds__(NTHREADS, 2)
lstm_persist(const float* __restrict__ x,   const float* __restrict__ Wih,
             const float* __restrict__ Whh, const float* __restrict__ bih,
             const float* __restrict__ bhh, const float* __restrict__ Wcls,
             const float* __restrict__ bcls, float* __restrict__ out,
             u64_t* __restrict__ hx,                 // [2][NGROUPS][1024], memset 0
             const unsigned short* __restrict__ xbf) // bf16 x or null
{
  __shared__ unsigned short hsm[2][4 * HID];      // 2 x 4KB A-tile (rows 0..3)
  __shared__ float clsh[BATCH_PG][UPB];           // final-h for classifier

  const int g    = blockIdx.x >> 3;
  const int blk  = blockIdx.x & 7;
  const int tid  = threadIdx.x;
  const int w    = tid >> 6;
  const int lane = tid & 63;
  const int lrow = lane & 15;   // A row / D col
  const int lk   = lane >> 4;   // K subgroup / (post-shuffle) batch index

  // ---- persistent weight fragments: 2 col-tiles x 18 K-chunks ----
  s16x8 wf[2][18];
  float bias[2];
#pragma unroll
  for (int n = 0; n < 2; ++n) {
    const int c    = w * 32 + n * 16 + lrow;       // local gate-col 0..255
    const int grow = (c & 3) * HID + blk * UPB + (c >> 2);
#pragma unroll
    for (int kk = 0; kk < 16; ++kk) {
      const float* p = Whh + (size_t)grow * HID + kk * 32 + lk * 8;
      wf[n][kk] = pack8(*(const f32x4*)p, *(const f32x4*)(p + 4));
    }
#pragma unroll
    for (int kk = 0; kk < 2; ++kk) {
      const float* p = Wih + (size_t)grow * IND + kk * 32 + lk * 8;
      wf[n][16 + kk] = pack8(*(const f32x4*)p, *(const f32x4*)(p + 4));
    }
    bias[n] = bih[grow] + bhh[grow];
  }

  const bool is_gg = ((lrow & 3) == 2);           // tanh gate column
  const bool arow  = (lrow < BATCH_PG);           // lanes holding real A rows
  float cst[2] = {0.f, 0.f};                      // c-state (batch lk, own col)

  // persistent A fragments: inactive lanes stay zero forever (masked loads)
  s16x8 ah[4] = {};
  s16x8 ax0 = {}, ax1 = {};

  const int xb = g * BATCH_PG + (lrow & 3);
  const float* xrow = x + (size_t)xb * (T_STEPS * IND) + lk * 8;
  const unsigned short* xbrow = XBF ? (xbf + (size_t)xb * (T_STEPS * IND) + lk * 8)
                                    : (const unsigned short*)nullptr;

  // prologue: x for t=0
  if (arow) {
    if (XBF) {
      ax0 = *(const s16x8*)(xbrow);
      ax1 = *(const s16x8*)(xbrow + 32);
    } else {
      ax0 = pack8(*(const f32x4*)xrow,        *(const f32x4*)(xrow + 4));
      ax1 = pack8(*(const f32x4*)(xrow + 32), *(const f32x4*)(xrow + 36));
    }
  }

  // precomputed scatter constants (DPP-paired dword writes)
  const bool evn = (tid & 1) == 0;
  const int  ue  = tid & ~1;
  const int  sc_base = ((ue >> 3) << 4) + (ue & 7) * 2;   // slot*16 + byte
  const int  addr01 = (evn ? 0 : 1024) + (sc_base ^ (evn ? 0 : (4 << 4)));
  const int  addr23 = (evn ? 2048 : 3072) + (sc_base ^ (evn ? (8 << 4) : (12 << 4)));

  for (int t = 0; t < T_STEPS; ++t) {
    const int rb = t & 1;
    const unsigned tg = (unsigned)t;

    // x MFMAs BEFORE the poll: depend only on prefetched ax, seed 4 chains
    f32x4 acc00 = {0.f, 0.f, 0.f, 0.f}, acc01 = {0.f, 0.f, 0.f, 0.f};
    f32x4 acc10 = {0.f, 0.f, 0.f, 0.f}, acc11 = {0.f, 0.f, 0.f, 0.f};
    acc00 = __builtin_amdgcn_mfma_f32_16x16x32_bf16(ax0, wf[0][16], acc00, 0, 0, 0);
    acc01 = __builtin_amdgcn_mfma_f32_16x16x32_bf16(ax1, wf[0][17], acc01, 0, 0, 0);
    acc10 = __builtin_amdgcn_mfma_f32_16x16x32_bf16(ax0, wf[1][16], acc10, 0, 0, 0);
    acc11 = __builtin_amdgcn_mfma_f32_16x16x32_bf16(ax1, wf[1][17], acc11, 0, 0, 0);

    // 2-deep ping-pong poll of own granule pair (flag IS data)
    const u64_t* gp = hx + ((size_t)(rb * NGROUPS + g) << 10) + 2 * tid;
    unsigned hp0, hp1;
    poll2(gp, tg, hp0, hp1);

    // scatter: pair halves with quad neighbor -> 2 full-dword LDS writes
    {
      char* hb = (char*)hsm[rb];
      const unsigned q0 = qswap(hp0), q1 = qswap(hp1);
      const unsigned v01 = evn ? ((hp0 & 0xffffu) | (q0 << 16))
                               : ((q0 >> 16) | (hp0 & 0xffff0000u));
      const unsigned v23 = evn ? ((hp1 & 0xffffu) | (q1 << 16))
                               : ((q1 >> 16) | (hp1 & 0xffff0000u));
      *(unsigned*)(hb + addr01) = v01;
      *(unsigned*)(hb + addr23) = v23;
    }

    __syncthreads();

    // PREFETCH next step's x now (lands during h-MFMA+gates)
    s16x8 axn0 = {}, axn1 = {};
    {
      const int tn = (t + 1 < T_STEPS) ? t + 1 : t;
      if (arow) {
        if (XBF) {
          axn0 = *(const s16x8*)(xbrow + (size_t)tn * IND);
          axn1 = *(const s16x8*)(xbrow + (size_t)tn * IND + 32);
        } else {
          const float* p = xrow + (size_t)tn * IND;
          axn0 = pack8(*(const f32x4*)p,        *(const f32x4*)(p + 4));
          axn1 = pack8(*(const f32x4*)(p + 32), *(const f32x4*)(p + 36));
        }
      }
    }

    // h MFMAs: masked reads (16 active lanes); two chains per col-tile
    const char* rowp = (const char*)hsm[rb] + lrow * 1024;
    const int rxor = lrow << 2;   // slot ^= (row*4); slot granule = 16B
#pragma unroll
    for (int kk4 = 0; kk4 < 4; ++kk4) {
      if (arow) {
#pragma unroll
        for (int j = 0; j < 4; ++j)
          ah[j] = *(const s16x8*)(rowp + (((16 * kk4 + 4 * j + lk) ^ rxor) << 4));
      }
#pragma unroll
      for (int j = 0; j < 4; ++j) {
        const int kk = kk4 * 4 + j;
        if (kk4 < 2) {
          acc00 = __builtin_amdgcn_mfma_f32_16x16x32_bf16(ah[j], wf[0][kk], acc00, 0, 0, 0);
          acc10 = __builtin_amdgcn_mfma_f32_16x16x32_bf16(ah[j], wf[1][kk], acc10, 0, 0, 0);
        } else {
          acc01 = __builtin_amdgcn_mfma_f32_16x16x32_bf16(ah[j], wf[0][kk], acc01, 0, 0, 0);
          acc11 = __builtin_amdgcn_mfma_f32_16x16x32_bf16(ah[j], wf[1][kk], acc11, 0, 0, 0);
        }
      }
    }

    // per col-tile: redistribute -> gates -> pack -> store (earliest visibility)
    u64_t* op = hx + ((size_t)((rb ^ 1) * NGROUPS + g) << 10);
    const u64_t ntg = (u64_t)(unsigned)(t + 1);
#pragma unroll
    for (int n = 0; n < 2; ++n) {
      const f32x4 aA = n ? acc10 : acc00;
      const f32x4 aB = n ? acc11 : acc01;
      const float s0 = aA[0] + aB[0], s1 = aA[1] + aB[1];
      const float s2 = aA[2] + aB[2], s3 = aA[3] + aB[3];
      const float b0 = __shfl(s0, lrow), b1 = __shfl(s1, lrow);
      const float b2 = __shfl(s2, lrow), b3 = __shfl(s3, lrow);
      const float myv = ((lk == 0) ? b0 : (lk == 1) ? b1 : (lk == 2) ? b2 : b3)
                        + bias[n];
      // gate nonlinearity: ONE (batch,col) per lane
      const float a  = is_gg ? (2.f * myv) : (-myv);
      const float e  = __expf(a);
      const float r1 = __builtin_amdgcn_rcpf(1.f + e);
      const float sg = is_gg ? (1.f - 2.f * r1) : r1;   // tanh or sigmoid
      const float vi = qbc<0x00>(sg);
      const float vf = qbc<0x55>(sg);
      const float vg = qbc<0xAA>(sg);
      const float vo = qbc<0xFF>(sg);
      const float c  = fmaf(vf, cst[n], vi * vg);
      cst[n] = c;
      const float th = 1.f - 2.f * __builtin_amdgcn_rcpf(1.f + __expf(2.f * c));
      const float hv = vo * th;
      // pack {batch lk, lk+1} via shfl_down(16); store granule immediately
      const unsigned hb16 = (unsigned)f2bf(hv);
      const unsigned pk   = hb16 | (__shfl_down(hb16, 16) << 16);
      if ((lrow & 3) == 0) {
        const int ul = w * 8 + n * 4 + (lrow >> 2);     // local unit 0..63
        if ((lk & 1) == 0) {
          const int gu = blk * UPB + ul;                // global unit 0..511
          ASTOREU(op + 2 * gu + (lk >> 1), ntg | ((u64_t)pk << 32));
        }
        if (t == T_STEPS - 1) clsh[lk][ul] = hv;
      }
    }

    ax0 = axn0; ax1 = axn1;
  }

  // ---- classifier: per-block partials over its 64 units ----
  __syncthreads();
  if (w == 0) {
#pragma unroll
    for (int b = 0; b < BATCH_PG; ++b) {
      const float hv = clsh[b][lane];
      for (int cls = 0; cls < 10; ++cls) {
        float v = hv * Wcls[(size_t)cls * HID + blk * UPB + lane];
#pragma unroll
        for (int m = 32; m >= 1; m >>= 1) v += __shfl_xor(v, m);
        if (lane == 0) {
          if (blk == 0) v += bcls[cls];
          atomicAdd(&out[(g * BATCH_PG + b) * 10 + cls], v);
        }
      }
    }
  }
}

extern "C" void kernel_launch(void* const* d_in, const int* in_sizes, int n_in,
                              void* d_out, int out_size, void* d_ws, size_t ws_size,
                              hipStream_t stream) {
  const float* x    = (const float*)d_in[0];
  const float* Wih  = (const float*)d_in[1];
  const float* Whh  = (const float*)d_in[2];
  const float* bih  = (const float*)d_in[3];
  const float* bhh  = (const float*)d_in[4];
  const float* Wcls = (const float*)d_in[5];
  const float* bcls = (const float*)d_in[6];
  float* out = (float*)d_out;

  u64_t* hx = (u64_t*)d_ws;   // [2][32][1024] u64 = 512 KiB
  const bool use_xbf = ws_size >= (size_t)XBF_OFF + (size_t)XBF_ELEMS * 2;
  unsigned short* xbf = use_xbf ? (unsigned short*)((uint8_t*)d_ws + XBF_OFF) : nullptr;

  // replay-safe re-init: zero tags (tag0 == step-0 data h=0) and output accum
  hipMemsetAsync(hx, 0, 2 * NGROUPS * 1024 * sizeof(u64_t), stream);
  hipMemsetAsync(out, 0, (size_t)out_size * sizeof(float), stream);
  if (use_xbf) xconv<<<dim3(2048), dim3(256), 0, stream>>>(x, xbf);

  const unsigned short* xbfc = xbf;
  void* args[] = {&x, &Wih, &Whh, &bih, &bhh, &Wcls, &bcls, &out, &hx, &xbfc};
  if (use_xbf) {
    hipError_t e = hipLaunchCooperativeKernel(
        reinterpret_cast<const void*>(&lstm_persist<true>), dim3(NBLK),
        dim3(NTHREADS), args, 0, stream);
    if (e != hipSuccess)
      lstm_persist<true><<<dim3(NBLK), dim3(NTHREADS), 0, stream>>>(
          x, Wih, Whh, bih, bhh, Wcls, bcls, out, hx, xbfc);
  } else {
    hipError_t e = hipLaunchCooperativeKernel(
        reinterpret_cast<const void*>(&lstm_persist<false>), dim3(NBLK),
        dim3(NTHREADS), args, 0, stream);
    if (e != hipSuccess)
      lstm_persist<false><<<dim3(NBLK), dim3(NTHREADS), 0, stream>>>(
          x, Wih, Whh, bih, bhh, Wcls, bcls, out, hx, xbfc);
  }
}